// Round 1
// baseline (23.243 us; speedup 1.0000x reference)
//
#include <hip/hip_runtime.h>

// GGNN: N=18 nodes, C=4 classes, A=14 alarms, H=20 hidden, O=8 out, T=5 steps.
// Tiny problem -> one fused kernel, one block, everything staged in LDS.

#define NN 18
#define CC 4
#define AA_ 14
#define HH 20
#define OO 8
#define TT 5

__global__ __launch_bounds__(512, 1) void ggnn_fused(
    const float* __restrict__ x,  const float* __restrict__ adj,
    const float* __restrict__ Wz, const float* __restrict__ bz,
    const float* __restrict__ Uz, const float* __restrict__ buz,
    const float* __restrict__ Wr, const float* __restrict__ br,
    const float* __restrict__ Ur, const float* __restrict__ bur,
    const float* __restrict__ Ww, const float* __restrict__ bw,
    const float* __restrict__ Uw, const float* __restrict__ bu,
    const float* __restrict__ Wo, const float* __restrict__ bo,
    const float* __restrict__ Wx, const float* __restrict__ bx,
    const float* __restrict__ Wy, const float* __restrict__ by,
    const float* __restrict__ w2, const float* __restrict__ b2,
    float* __restrict__ outp)
{
    __shared__ float sWz[HH*2*HH], sWr[HH*2*HH], sWw[HH*2*HH];
    __shared__ float sUz[HH*HH], sUr[HH*HH], sUw[HH*HH];
    __shared__ float sbz[HH], sbuz[HH], sbr[HH], sbur[HH], sbw[HH], sbu[HH];
    __shared__ float sWo[OO*2*HH], sbo[OO], sWx[OO*HH], sbx[OO], sWy[OO*HH], sby[OO];
    __shared__ float sw2[OO], sb2;
    __shared__ float sAdj[NN*NN], sX[NN*HH];
    __shared__ float h[NN*HH], aa[NN*2*HH], rr[NN*HH], zz[NN*HH], ws[NN*HH];
    __shared__ float sOut[NN*OO], sCf[CC*OO], sAf[AA_*OO], sRfc[CC*AA_];

    const int tid = threadIdx.x;

    // ---- stage everything into LDS ----
    for (int i = tid; i < HH*2*HH; i += 512) { sWz[i]=Wz[i]; sWr[i]=Wr[i]; sWw[i]=Ww[i]; }
    for (int i = tid; i < HH*HH;  i += 512) { sUz[i]=Uz[i]; sUr[i]=Ur[i]; sUw[i]=Uw[i]; }
    if (tid < HH) { sbz[tid]=bz[tid]; sbuz[tid]=buz[tid]; sbr[tid]=br[tid];
                    sbur[tid]=bur[tid]; sbw[tid]=bw[tid]; sbu[tid]=bu[tid]; }
    for (int i = tid; i < OO*2*HH; i += 512) sWo[i]=Wo[i];
    for (int i = tid; i < OO*HH;  i += 512) { sWx[i]=Wx[i]; sWy[i]=Wy[i]; }
    if (tid < OO) { sbo[tid]=bo[tid]; sbx[tid]=bx[tid]; sby[tid]=by[tid]; sw2[tid]=w2[tid]; }
    if (tid == 0) sb2 = b2[0];
    for (int i = tid; i < NN*NN; i += 512) sAdj[i]=adj[i];
    for (int i = tid; i < NN*HH; i += 512) { float v = x[i]; sX[i]=v; h[i]=v; }
    __syncthreads();

    // ---- T GRU steps ----
    for (int t = 0; t < TT; ++t) {
        // phase 1: a = [adj @ h, adj.T @ h]   -> [18, 40]
        for (int i = tid; i < NN*2*HH; i += 512) {
            int n = i / (2*HH), k = i % (2*HH);
            float s = 0.f;
            if (k < HH) {
                #pragma unroll
                for (int m = 0; m < NN; ++m) s += sAdj[n*NN+m]*h[m*HH+k];
            } else {
                int kk = k - HH;
                #pragma unroll
                for (int m = 0; m < NN; ++m) s += sAdj[m*NN+n]*h[m*HH+kk];
            }
            aa[i] = s;
        }
        __syncthreads();
        // phase 2: z, r (sigmoid), and the W-part of the candidate
        if (tid < NN*HH) {
            int n = tid / HH, i = tid % HH;
            float sz = sbz[i] + sbuz[i];
            float sr = sbr[i] + sbur[i];
            float sw_ = sbw[i];
            #pragma unroll
            for (int k = 0; k < 2*HH; ++k) {
                float av = aa[n*2*HH+k];
                sz += sWz[i*2*HH+k]*av;
                sr += sWr[i*2*HH+k]*av;
                sw_ += sWw[i*2*HH+k]*av;
            }
            #pragma unroll
            for (int j = 0; j < HH; ++j) {
                float hv = h[n*HH+j];
                sz += sUz[i*HH+j]*hv;
                sr += sUr[i*HH+j]*hv;
            }
            zz[tid] = 1.f/(1.f+expf(-sz));
            rr[tid] = 1.f/(1.f+expf(-sr));
            ws[tid] = sw_;
        }
        __syncthreads();
        // phase 3: candidate hg and new h
        float hnew = 0.f;
        if (tid < NN*HH) {
            int n = tid / HH, i = tid % HH;
            float s = ws[tid] + sbu[i];
            #pragma unroll
            for (int j = 0; j < HH; ++j) s += sUw[i*HH+j]*rr[n*HH+j]*h[n*HH+j];
            float hg = tanhf(s);
            float zv = zz[tid];
            hnew = (1.f - zv)*h[tid] + zv*hg;
        }
        __syncthreads();
        if (tid < NN*HH) h[tid] = hnew;
        __syncthreads();
    }

    // ---- epilogue: out / cfcx / afcy in parallel thread ranges ----
    if (tid < NN*OO) {                       // out = tanh([h,x] @ Wo.T + bo)  [18,8]
        int n = tid / OO, o = tid % OO;
        float s = sbo[o];
        #pragma unroll
        for (int j = 0; j < HH; ++j) s += sWo[o*2*HH+j]*h[n*HH+j];
        #pragma unroll
        for (int j = 0; j < HH; ++j) s += sWo[o*2*HH+HH+j]*sX[n*HH+j];
        sOut[tid] = tanhf(s);
    } else if (tid >= 256 && tid < 256 + CC*OO) {   // cfcx [4,8]
        int i = tid - 256;
        int c = i / OO, o = i % OO;
        float s = sbx[o];
        #pragma unroll
        for (int j = 0; j < HH; ++j) s += sWx[o*HH+j]*h[c*HH+j];
        sCf[i] = tanhf(s);
    } else if (tid >= 320 && tid < 320 + AA_*OO) {  // afcy [14,8]
        int i = tid - 320;
        int a = i / OO, o = i % OO;
        float s = sby[o];
        #pragma unroll
        for (int j = 0; j < HH; ++j) s += sWy[o*HH+j]*h[(CC+a)*HH+j];
        sAf[i] = tanhf(s);
    }
    __syncthreads();

    // rfc[c][a] = sigmoid(sum_o cf*af*w2 + b2) * adj[c][4+a]
    if (tid < CC*AA_) {
        int c = tid / AA_, a = tid % AA_;
        float s = sb2;
        #pragma unroll
        for (int o = 0; o < OO; ++o) s += sCf[c*OO+o]*sAf[a*OO+o]*sw2[o];
        sRfc[tid] = (1.f/(1.f+expf(-s))) * sAdj[c*NN + CC + a];
    }
    __syncthreads();

    // final [C][1+A][O] = 480 floats
    if (tid < CC*(1+AA_)*OO) {
        int c = tid / ((1+AA_)*OO);
        int rem = tid % ((1+AA_)*OO);
        int s_ = rem / OO, o = rem % OO;
        float v;
        if (s_ == 0) v = sOut[c*OO+o];
        else         v = sOut[(CC + s_-1)*OO + o] * sRfc[c*AA_ + (s_-1)];
        outp[tid] = v;
    }
}

extern "C" void kernel_launch(void* const* d_in, const int* in_sizes, int n_in,
                              void* d_out, int out_size, void* d_ws, size_t ws_size,
                              hipStream_t stream) {
    (void)in_sizes; (void)n_in; (void)d_ws; (void)ws_size; (void)out_size;
    const float* x   = (const float*)d_in[0];
    const float* adj = (const float*)d_in[1];
    const float* Wz  = (const float*)d_in[2];
    const float* bz  = (const float*)d_in[3];
    const float* Uz  = (const float*)d_in[4];
    const float* buz = (const float*)d_in[5];
    const float* Wr  = (const float*)d_in[6];
    const float* br  = (const float*)d_in[7];
    const float* Ur  = (const float*)d_in[8];
    const float* bur = (const float*)d_in[9];
    const float* Ww  = (const float*)d_in[10];
    const float* bw  = (const float*)d_in[11];
    const float* Uw  = (const float*)d_in[12];
    const float* bu  = (const float*)d_in[13];
    const float* Wo  = (const float*)d_in[14];
    const float* bo  = (const float*)d_in[15];
    const float* Wx  = (const float*)d_in[16];
    const float* bx  = (const float*)d_in[17];
    const float* Wy  = (const float*)d_in[18];
    const float* by  = (const float*)d_in[19];
    const float* w2  = (const float*)d_in[20];
    const float* b2  = (const float*)d_in[21];
    float* outp = (float*)d_out;

    ggnn_fused<<<1, 512, 0, stream>>>(x, adj, Wz, bz, Uz, buz, Wr, br, Ur, bur,
                                      Ww, bw, Uw, bu, Wo, bo, Wx, bx, Wy, by,
                                      w2, b2, outp);
}

// Round 2
// 20.220 us; speedup vs baseline: 1.1495x; 1.1495x over previous
//
#include <hip/hip_runtime.h>

// GGNN: N=18, C=4, A=14, H=20, O=8, T=5. One fused single-block kernel.
// Layout: everything recurrent stored TRANSPOSED in LDS as [feat][node]
// (node fastest -> 18 consecutive dwords per access group: conflict-free).
// GRU weights hoisted to registers (reused 5x). Gates split across
// wave-aligned thread groups: even waves = z gate (+Ww first half),
// odd waves = r gate (+Ww second half).

__device__ __forceinline__ float fsig(float x){ return 1.0f/(1.0f+__expf(-x)); }
__device__ __forceinline__ float ftnh(float x){ return 1.0f - 2.0f/(__expf(2.0f*x)+1.0f); }

__global__ __launch_bounds__(768, 1) void ggnn_fused(
    const float* __restrict__ x,  const float* __restrict__ adj,
    const float* __restrict__ Wz, const float* __restrict__ bz,
    const float* __restrict__ Uz, const float* __restrict__ buz,
    const float* __restrict__ Wr, const float* __restrict__ br,
    const float* __restrict__ Ur, const float* __restrict__ bur,
    const float* __restrict__ Ww, const float* __restrict__ bw,
    const float* __restrict__ Uw, const float* __restrict__ bu,
    const float* __restrict__ Wo, const float* __restrict__ bo,
    const float* __restrict__ Wx, const float* __restrict__ bx,
    const float* __restrict__ Wy, const float* __restrict__ by,
    const float* __restrict__ w2, const float* __restrict__ b2,
    float* __restrict__ outp)
{
  __shared__ float sAdj[324];          // adj row-major [18][18]
  __shared__ float hA[360], hB[360];   // h transposed [20][18]
  __shared__ float aaT[720];           // a transposed [40][18]
  __shared__ float rrT[360], ws1[360]; // r gate + Ww-hi partial, [20][18]
  __shared__ float sOut[144], sCf[32], sAf[112], sRfc[56];

  const int tid = threadIdx.x;

  // ---- P2/P3 mapping: gate = wave parity (wave-uniform, no divergence) ----
  const int g    = (tid >> 6) & 1;                 // 0: z gate, 1: r gate
  const int idx  = (tid >> 7) * 64 + (tid & 63);   // 0..383 per gate
  const bool act2 = (idx < 360);
  const int i2 = idx / 18, n2 = idx % 18;

  // ---- P1 mapping: one (k,n) of aaT per thread, k in 0..39 ----
  const bool act1 = (tid < 720);
  const int n1 = tid % 18;
  const int kk = tid / 18;            // 0..39
  const int k1 = kk % 20;
  const int abase = (kk < 20) ? (n1 * 18) : n1;    // in_mat: adj[n][m]; out_mat: adj[m][n]
  const int astep = (kk < 20) ? 1 : 18;

  // ---- stage adj + h0 = x (transposed) ----
  if (tid < 324) sAdj[tid] = adj[tid];
  if (tid < 360) { int j = tid/18, n = tid%18; hA[j*18+n] = x[n*20+j]; }

  // ---- hoist GRU weights into registers (reused all 5 steps) ----
  float4 w4[10], u4[5], wh4[5], uw4[5];
  float bias1 = 0.f, bwi = 0.f, bui = 0.f;
  if (act2) {
    const float* Wg = g ? Wr : Wz;
    const float* Ug = g ? Ur : Uz;
    #pragma unroll
    for (int q=0;q<10;q++) w4[q] = *(const float4*)(Wg + i2*40 + 4*q);
    #pragma unroll
    for (int q=0;q<5;q++){
      u4[q]  = *(const float4*)(Ug + i2*20 + 4*q);
      wh4[q] = *(const float4*)(Ww + i2*40 + g*20 + 4*q);
    }
    if (g == 0){
      bias1 = bz[i2] + buz[i2];
      bwi   = bw[i2];
      bui   = bu[i2];
      #pragma unroll
      for (int q=0;q<5;q++) uw4[q] = *(const float4*)(Uw + i2*20 + 4*q);
    } else {
      bias1 = br[i2] + bur[i2];
    }
  }
  __syncthreads();

  float* hc = hA;
  float* hn = hB;
  float zreg = 0.f, sw0 = 0.f;   // z gate + Ww-lo partial live across P2->P3

  for (int t=0;t<5;t++){
    // ---- P1: aaT[k][n] = sum_m M[n][m] * h[m][k%20] ----
    if (act1){
      float s = 0.f;
      #pragma unroll
      for (int m=0;m<18;m++) s += sAdj[abase + m*astep] * hc[k1*18+m];
      aaT[kk*18 + n1] = s;
    }
    __syncthreads();

    // ---- P2: gate pre-activations (weights in registers) ----
    if (act2){
      float sg = bias1, sw = bwi;
      #pragma unroll
      for (int q=0;q<10;q++){
        float a0 = aaT[(4*q+0)*18+n2];
        float a1 = aaT[(4*q+1)*18+n2];
        float a2 = aaT[(4*q+2)*18+n2];
        float a3 = aaT[(4*q+3)*18+n2];
        sg += w4[q].x*a0 + w4[q].y*a1 + w4[q].z*a2 + w4[q].w*a3;
        if (g==0 && q<5)  { sw += wh4[q].x*a0 + wh4[q].y*a1 + wh4[q].z*a2 + wh4[q].w*a3; }
        if (g==1 && q>=5) { const float4 W = wh4[q-5]; sw += W.x*a0 + W.y*a1 + W.z*a2 + W.w*a3; }
      }
      #pragma unroll
      for (int q=0;q<5;q++){
        float h0 = hc[(4*q+0)*18+n2];
        float h1 = hc[(4*q+1)*18+n2];
        float h2 = hc[(4*q+2)*18+n2];
        float h3 = hc[(4*q+3)*18+n2];
        sg += u4[q].x*h0 + u4[q].y*h1 + u4[q].z*h2 + u4[q].w*h3;
      }
      if (g == 0){
        zreg = fsig(sg);     // stays in registers (same thread does P3)
        sw0  = sw;
      } else {
        rrT[i2*18+n2] = fsig(sg);
        ws1[i2*18+n2] = sw;
      }
    }
    __syncthreads();

    // ---- P3: candidate + h update (even waves only) ----
    if (g == 0 && act2){
      float s = bui + sw0 + ws1[i2*18+n2];
      #pragma unroll
      for (int q=0;q<5;q++){
        float u0=u4[0].x; // dummy to keep pragma happy
        (void)u0;
        s += uw4[q].x * rrT[(4*q+0)*18+n2] * hc[(4*q+0)*18+n2];
        s += uw4[q].y * rrT[(4*q+1)*18+n2] * hc[(4*q+1)*18+n2];
        s += uw4[q].z * rrT[(4*q+2)*18+n2] * hc[(4*q+2)*18+n2];
        s += uw4[q].w * rrT[(4*q+3)*18+n2] * hc[(4*q+3)*18+n2];
      }
      float hg = ftnh(s);
      hn[i2*18+n2] = (1.f - zreg)*hc[i2*18+n2] + zreg*hg;
    }
    __syncthreads();
    float* tmp = hc; hc = hn; hn = tmp;
  }

  // ---- epilogue ----
  if (tid < 144){                                  // out[n][o] = tanh([h,x]@Wo.T+bo)
    int n_ = tid/8, o = tid%8;
    float s = bo[o];
    #pragma unroll
    for (int q=0;q<5;q++){
      float4 w = *(const float4*)(Wo + o*40 + 4*q);
      s += w.x*hc[(4*q+0)*18+n_] + w.y*hc[(4*q+1)*18+n_]
         + w.z*hc[(4*q+2)*18+n_] + w.w*hc[(4*q+3)*18+n_];
    }
    #pragma unroll
    for (int q=0;q<5;q++){
      float4 w  = *(const float4*)(Wo + o*40 + 20 + 4*q);
      float4 xv = *(const float4*)(x + n_*20 + 4*q);
      s += w.x*xv.x + w.y*xv.y + w.z*xv.z + w.w*xv.w;
    }
    sOut[tid] = ftnh(s);
  } else if (tid >= 192 && tid < 224){             // cfcx [4][8]
    int ii = tid-192; int c = ii/8, o = ii%8;
    float s = bx[o];
    #pragma unroll
    for (int q=0;q<5;q++){
      float4 w = *(const float4*)(Wx + o*20 + 4*q);
      s += w.x*hc[(4*q+0)*18+c] + w.y*hc[(4*q+1)*18+c]
         + w.z*hc[(4*q+2)*18+c] + w.w*hc[(4*q+3)*18+c];
    }
    sCf[ii] = ftnh(s);
  } else if (tid >= 256 && tid < 368){             // afcy [14][8]
    int ii = tid-256; int a = ii/8, o = ii%8;
    float s = by[o];
    #pragma unroll
    for (int q=0;q<5;q++){
      float4 w = *(const float4*)(Wy + o*20 + 4*q);
      s += w.x*hc[(4*q+0)*18+4+a] + w.y*hc[(4*q+1)*18+4+a]
         + w.z*hc[(4*q+2)*18+4+a] + w.w*hc[(4*q+3)*18+4+a];
    }
    sAf[ii] = ftnh(s);
  }
  __syncthreads();

  if (tid < 56){                                   // rfc[c][a]
    int c = tid/14, a = tid%14;
    float4 w20 = *(const float4*)(w2);
    float4 w21 = *(const float4*)(w2+4);
    const float* cf = &sCf[c*8];
    const float* af = &sAf[a*8];
    float s = b2[0];
    s += cf[0]*af[0]*w20.x + cf[1]*af[1]*w20.y + cf[2]*af[2]*w20.z + cf[3]*af[3]*w20.w;
    s += cf[4]*af[4]*w21.x + cf[5]*af[5]*w21.y + cf[6]*af[6]*w21.z + cf[7]*af[7]*w21.w;
    sRfc[tid] = fsig(s) * sAdj[c*18 + 4 + a];
  }
  __syncthreads();

  if (tid < 480){                                  // final [4][15][8]
    int c = tid/120, rem = tid%120, s_ = rem/8, o = rem%8;
    float v = (s_ == 0) ? sOut[c*8+o]
                        : sOut[(3+s_)*8+o] * sRfc[c*14 + (s_-1)];
    outp[tid] = v;
  }
}

extern "C" void kernel_launch(void* const* d_in, const int* in_sizes, int n_in,
                              void* d_out, int out_size, void* d_ws, size_t ws_size,
                              hipStream_t stream) {
  (void)in_sizes; (void)n_in; (void)d_ws; (void)ws_size; (void)out_size;
  const float* x   = (const float*)d_in[0];
  const float* adj = (const float*)d_in[1];
  const float* Wz  = (const float*)d_in[2];
  const float* bz  = (const float*)d_in[3];
  const float* Uz  = (const float*)d_in[4];
  const float* buz = (const float*)d_in[5];
  const float* Wr  = (const float*)d_in[6];
  const float* br  = (const float*)d_in[7];
  const float* Ur  = (const float*)d_in[8];
  const float* bur = (const float*)d_in[9];
  const float* Ww  = (const float*)d_in[10];
  const float* bw  = (const float*)d_in[11];
  const float* Uw  = (const float*)d_in[12];
  const float* bu  = (const float*)d_in[13];
  const float* Wo  = (const float*)d_in[14];
  const float* bo  = (const float*)d_in[15];
  const float* Wx  = (const float*)d_in[16];
  const float* bx  = (const float*)d_in[17];
  const float* Wy  = (const float*)d_in[18];
  const float* by  = (const float*)d_in[19];
  const float* w2  = (const float*)d_in[20];
  const float* b2  = (const float*)d_in[21];
  float* outp = (float*)d_out;

  ggnn_fused<<<1, 768, 0, stream>>>(x, adj, Wz, bz, Uz, buz, Wr, br, Ur, bur,
                                    Ww, bw, Uw, bu, Wo, bo, Wx, bx, Wy, by,
                                    w2, b2, outp);
}